// Round 14
// baseline (199.120 us; speedup 1.0000x reference)
//
#include <hip/hip_runtime.h>
#include <stdint.h>

#define NMOL 16
#define MS   4096
#define NA   32
#define NP   512
#define BM   64
#define TBL  65536u

typedef __attribute__((ext_vector_type(4))) float  f32x4;
typedef __attribute__((ext_vector_type(4))) unsigned int u32x4;
typedef __attribute__((ext_vector_type(2))) unsigned int u32x2;
typedef __attribute__((ext_vector_type(8))) short  s16x8;
typedef __attribute__((ext_vector_type(8))) _Float16 f16x8;
typedef unsigned int uint;
typedef unsigned short ushort;

// ws layout
#define WS_DMF_OFF   0u
#define WS_DMF_SZ    (16u*512u*512u*2u)
#define WS_M2A_OFF   (WS_DMF_OFF + WS_DMF_SZ)
#define WS_M2A_SZ    (16u*512u*4u)
#define WS_M2B_OFF   (WS_M2A_OFF + WS_M2A_SZ)
#define WS_M2B_SZ    (16u*512u*4u)
#define WS_ALPH_OFF  (WS_M2B_OFF + WS_M2B_SZ)
#define WS_SCR_OFF   (16u << 20)          // probe scratch: 16MB + V*4MB

// WFN symmetry table packed px | py<<4 | pz<<8
__device__ __constant__ uint c_pw[20] = {
  0x000,
  0x001, 0x010, 0x100,
  0x002, 0x020, 0x200, 0x011, 0x101, 0x110,
  0x003, 0x030, 0x300, 0x012, 0x102, 0x120, 0x021, 0x201, 0x210, 0x111
};

__device__ __forceinline__ float cvt16lo(uint u) {
  float r; asm("v_cvt_f32_f16 %0, %1" : "=v"(r) : "v"(u)); return r;
}
__device__ __forceinline__ float cvt16hi(uint u) {
  uint s = u >> 16; float r; asm("v_cvt_f32_f16 %0, %1" : "=v"(r) : "v"(s)); return r;
}
__device__ __forceinline__ uint pkmul(uint a, uint b) {
  uint r; asm("v_pk_mul_f16 %0, %1, %2" : "=v"(r) : "v"(a), "v"(b)); return r;
}
__device__ __forceinline__ uint f2h2(float a, float b) {
  union { __fp16 __attribute__((ext_vector_type(2))) h; uint u; } x;
  x.h = __builtin_amdgcn_cvt_pkrtz(a, b);
  return x.u;
}
__device__ __forceinline__ short f2hs(float f) {
  _Float16 h = (_Float16)f;
  union { _Float16 h; short s; } x; x.h = h; return x.s;
}
__device__ __forceinline__ f16x8 mkfrag(u32x2 lo, u32x2 hi) {
  union { uint u[4]; f16x8 v; } x;
  x.u[0] = lo[0]; x.u[1] = lo[1]; x.u[2] = hi[0]; x.u[3] = hi[1];
  return x.v;
}

// ---- dm fp32 [n][p][q] -> W' = symmetrized upper-tri, f16 fragment-packed (R13).
__global__ void dm_pack(const float* __restrict__ dm, short* __restrict__ dmF,
                        const int* __restrict__ centers, const int* __restrict__ sym,
                        const float* __restrict__ expg,
                        uint* __restrict__ m2a, uint* __restrict__ m2b,
                        float* __restrict__ alphaS) {
  __shared__ float tile[NP * 33];
  const int Qp = blockIdx.x, n = blockIdx.y;
  const int t = threadIdx.x;
  const float* base = dm + (size_t)n * NP * NP;
  const float* src  = base + Qp * 32;
#pragma unroll
  for (int i = 0; i < 64; ++i) {
    int e = t + 256 * i;
    int p = e >> 5, c = e & 31;
    tile[p * 33 + c] = src[(size_t)p * NP + c];
  }
  if (n == 0) {
#pragma unroll
    for (int kk = 0; kk < 2; ++kk) {
      int i = Qp * 512 + t + 256 * kk;
      int craw = centers[i], s = sym[i];
      bool valid = (craw >= 0);
      uint c = (uint)((valid ? craw : 0) & (NA - 1));
      int si = valid ? s : 0;
      si = (si >= 0 && si < 20) ? si : 0;
      uint pw = c_pw[si];
      uint d = (pw & 15u) + ((pw >> 4) & 15u) + ((pw >> 8) & 15u);
      uint h[3]; int k = 0;
#pragma unroll
      for (uint ax = 0; ax < 3; ++ax) {
        uint e2 = (pw >> (4 * ax)) & 15u;
        for (uint r = 0; r < e2; ++r) if (k < 3) h[k++] = c * 512u + ax * 128u;
      }
      while (k < 3) h[k++] = c * 512u;
      m2a[i] = h[0] | (h[1] << 16);
      m2b[i] = h[2] | (d << 14) | (c << 16);
      alphaS[i] = (valid ? -expg[i] : -1e5f) * 1.44269504088896f;
    }
  }
  __syncthreads();
#pragma unroll
  for (int it = 0; it < 8; ++it) {
    int v = t + 256 * it;
    int qq = v >> 10, vv = v & 1023;
    int kblk = vv >> 6, l = vv & 63;
    int p0 = kblk * 32 + ((l >> 4) << 3);
    int col = l & 15;
    int q = (Qp * 2 + qq) * 16 + col;
    f32x4 r0 = *(const f32x4*)(base + (size_t)q * NP + p0);
    f32x4 r1 = *(const f32x4*)(base + (size_t)q * NP + p0 + 4);
    s16x8 o;
#pragma unroll
    for (int j = 0; j < 8; ++j) {
      int p = p0 + j;
      float tpq = tile[p * 33 + qq * 16 + col];
      float rv = (j < 4) ? r0[j] : r1[j - 4];
      float w = (p < q) ? (tpq + rv) : ((p == q) ? tpq : 0.0f);
      o[j] = f2hs(w);
    }
    short* dst = dmF + ((size_t)(n * 32 + Qp * 2 + qq) * 16) * 512;
    *(s16x8*)(dst + (size_t)vv * 8) = o;
  }
}

#define MFMA16(a, b, c) __builtin_amdgcn_mfma_f32_16x16x32_f16(a, b, c, 0, 0, 0)

#define ISSUE_TR(AK) \
  asm volatile("ds_read_b64_tr_b16 %0, %1 offset:0"     : "=v"(l0) : "v"(AK)); \
  asm volatile("ds_read_b64_tr_b16 %0, %1 offset:512"   : "=v"(g0) : "v"(AK)); \
  asm volatile("ds_read_b64_tr_b16 %0, %1 offset:16384" : "=v"(l1) : "v"(AK)); \
  asm volatile("ds_read_b64_tr_b16 %0, %1 offset:16896" : "=v"(g1) : "v"(AK)); \
  asm volatile("ds_read_b64_tr_b16 %0, %1 offset:32768" : "=v"(l2) : "v"(AK)); \
  asm volatile("ds_read_b64_tr_b16 %0, %1 offset:33280" : "=v"(g2) : "v"(AK)); \
  asm volatile("ds_read_b64_tr_b16 %0, %1 offset:49152" : "=v"(l3) : "v"(AK)); \
  asm volatile("ds_read_b64_tr_b16 %0, %1 offset:49664" : "=v"(g3) : "v"(AK));

#define ISSUE_TR_B(AK) \
  asm volatile("ds_read_b64_tr_b16 %0, %1 offset:0"     : "=v"(r0) : "v"(AK)); \
  asm volatile("ds_read_b64_tr_b16 %0, %1 offset:512"   : "=v"(s0) : "v"(AK)); \
  asm volatile("ds_read_b64_tr_b16 %0, %1 offset:16384" : "=v"(r1) : "v"(AK)); \
  asm volatile("ds_read_b64_tr_b16 %0, %1 offset:16896" : "=v"(s1) : "v"(AK)); \
  asm volatile("ds_read_b64_tr_b16 %0, %1 offset:32768" : "=v"(r2) : "v"(AK)); \
  asm volatile("ds_read_b64_tr_b16 %0, %1 offset:33280" : "=v"(s2) : "v"(AK)); \
  asm volatile("ds_read_b64_tr_b16 %0, %1 offset:49152" : "=v"(r3) : "v"(AK)); \
  asm volatile("ds_read_b64_tr_b16 %0, %1 offset:49664" : "=v"(s3) : "v"(AK));

#define FINISH_TRIP(KBLK) do { \
  f16x8 bf0, bf1, bf2, bf3; \
  const bool c0 = (KBLK) <= kq0, c1 = (KBLK) <= kq1, c2 = (KBLK) <= kq2; \
  if (c0) bf0 = *(const f16x8*)(bp0 + (KBLK) * 512); \
  if (c1) bf1 = *(const f16x8*)(bp1 + (KBLK) * 512); \
  if (c2) bf2 = *(const f16x8*)(bp2 + (KBLK) * 512); \
  bf3 = *(const f16x8*)(bp3 + (KBLK) * 512); \
  asm volatile("s_waitcnt lgkmcnt(0)"); \
  __builtin_amdgcn_sched_barrier(0); \
  f16x8 af0 = mkfrag(l0, g0), af1 = mkfrag(l1, g1); \
  f16x8 af2 = mkfrag(l2, g2), af3 = mkfrag(l3, g3); \
  __builtin_amdgcn_s_setprio(1); \
  if (c0) { acc[0][0]=MFMA16(af0,bf0,acc[0][0]); acc[1][0]=MFMA16(af1,bf0,acc[1][0]); \
            acc[2][0]=MFMA16(af2,bf0,acc[2][0]); acc[3][0]=MFMA16(af3,bf0,acc[3][0]); } \
  if (c1) { acc[0][1]=MFMA16(af0,bf1,acc[0][1]); acc[1][1]=MFMA16(af1,bf1,acc[1][1]); \
            acc[2][1]=MFMA16(af2,bf1,acc[2][1]); acc[3][1]=MFMA16(af3,bf1,acc[3][1]); } \
  if (c2) { acc[0][2]=MFMA16(af0,bf2,acc[0][2]); acc[1][2]=MFMA16(af1,bf2,acc[1][2]); \
            acc[2][2]=MFMA16(af2,bf2,acc[2][2]); acc[3][2]=MFMA16(af3,bf2,acc[3][2]); } \
  acc[0][3]=MFMA16(af0,bf3,acc[0][3]); acc[1][3]=MFMA16(af1,bf3,acc[1][3]); \
  acc[2][3]=MFMA16(af2,bf3,acc[2][3]); acc[3][3]=MFMA16(af3,bf3,acc[3][3]); \
  __builtin_amdgcn_s_setprio(0); \
} while (0)

// phase 1a + 1b as callable pieces (shared by real kernel and probe V1)
__device__ __forceinline__ void build_table(char* smem, const float* dvg, int t) {
#pragma unroll
  for (int k = 0; k < 4; ++k) {
    int idx = t + 512 * k;
    int m = idx >> 5, c = idx & 31;
    const float* p = dvg + (m * NA + c) * 3;
    float x = p[0], y = p[1], z = p[2];
    float r2 = fmaf(x, x, fmaf(y, y, z * z));
    uint base = TBL + (uint)c * 512u
              + ((uint)((m >> 3) ^ (c & 7)) << 4) + (uint)((m & 7) << 1);
    *(_Float16*)(smem + base)       = (_Float16)x;
    *(_Float16*)(smem + base + 128) = (_Float16)y;
    *(_Float16*)(smem + base + 256) = (_Float16)z;
    *(_Float16*)(smem + base + 384) = (_Float16)r2;
  }
}

__device__ __forceinline__ void basis_phase(char* smem, uint ma, uint mb, float al, int p) {
  const uint alp = f2h2(al, al);
  const uint h0 = ma & 0xFFFFu, h1 = ma >> 16;
  const uint h2v = mb & 0x3FFFu;
  const uint d  = (mb >> 14) & 3u;
  const uint cs = (h0 >> 9) & 7u;
  const uint rh = (h0 & 0xFE00u) + 384u;
  const bool ge2 = (d >= 2), eq3 = (d == 3), eq0 = (d == 0);
  const uint wbase = ((uint)(p >> 5) << 10) + (((uint)(p >> 2) & 1u) << 9)
                   + ((((uint)p & 31u) >> 3) << 7) + (((uint)p & 3u) << 5);
#pragma unroll
  for (int j = 0; j < 8; ++j) {
    uint off = (uint)((j ^ (int)cs) << 4);
    u32x4 qr = *(const u32x4*)(smem + TBL + rh + off);
    u32x4 q0, q1, q2;
    if (!eq0) q0 = *(const u32x4*)(smem + TBL + h0 + off);
    if (ge2)  q1 = *(const u32x4*)(smem + TBL + h1 + off);
    if (eq3)  q2 = *(const u32x4*)(smem + TBL + h2v + off);
    uint res[4];
#pragma unroll
    for (int w = 0; w < 4; ++w) {
      uint m_ = eq0 ? 0x3C003C00u : q0[w];
      if (ge2) m_ = pkmul(m_, q1[w]);
      if (eq3) m_ = pkmul(m_, q2[w]);
      uint ap = pkmul(alp, qr[w]);
      float a0 = cvt16lo(ap), a1 = cvt16hi(ap);
      float e0, e1;
      asm("v_exp_f32 %0, %1" : "=v"(e0) : "v"(a0));
      asm("v_exp_f32 %0, %1" : "=v"(e1) : "v"(a1));
      res[w] = pkmul(m_, f2h2(e0, e1));
    }
    *(u32x4*)(smem + wbase + ((uint)(j >> 1) << 14) + ((uint)(j & 1) << 4))
        = *(u32x4*)res;
  }
}

// ---------------- real fused kernel: byte-identical behavior to R13 ------------
__launch_bounds__(512, 4)
__global__ void wfn_fused8(const float* __restrict__ dv,
                           const uint* __restrict__ m2aG,
                           const uint* __restrict__ m2bG,
                           const float* __restrict__ alG,
                           const short* __restrict__ dmF,
                           float* __restrict__ out) {
  __shared__ __align__(16) char smem[81920];
  const int t = threadIdx.x;
  const int bid = ((blockIdx.x & 7) << 7) + (blockIdx.x >> 3);
  const int n  = bid >> 6;
  const int m0 = (bid & 63) * BM;

  build_table(smem, dv + (size_t)(n * MS + m0) * (NA * 3), t);
  __syncthreads();
  basis_phase(smem, m2aG[n * NP + t], m2bG[n * NP + t], alG[n * NP + t], t);
  __syncthreads();

  const int lane = t & 63, wv = t >> 6, li = lane & 15, kg = lane >> 4;
  const uint lane8 = (uint)lane << 3;
  const short* dmFn = dmF + (size_t)n * (32 * 16 * 512);

  f32x4 acc[4][4];
#pragma unroll
  for (int rf = 0; rf < 4; ++rf)
#pragma unroll
    for (int qf = 0; qf < 4; ++qf)
      acc[rf][qf] = (f32x4){0.f, 0.f, 0.f, 0.f};

  const short* bp0 = dmFn + ((size_t)((wv)      * 16) * 512) + lane * 8;
  const short* bp1 = dmFn + ((size_t)((wv + 8)  * 16) * 512) + lane * 8;
  const short* bp2 = dmFn + ((size_t)((wv + 16) * 16) * 512) + lane * 8;
  const short* bp3 = dmFn + ((size_t)((wv + 24) * 16) * 512) + lane * 8;
  const int kq0 = wv >> 1, kq1 = (wv + 8) >> 1, kq2 = (wv + 16) >> 1;
  const int kmaxw = (wv + 24) >> 1;

  for (int kblk = 0; kblk <= kmaxw; ++kblk) {
    uint ak = lane8 + ((uint)kblk << 10);
    u32x2 l0, g0, l1, g1, l2, g2, l3, g3;
    ISSUE_TR(ak);
    FINISH_TRIP(kblk);
  }

  float part[16];
#pragma unroll
  for (int x = 0; x < 16; ++x) part[x] = 0.0f;
  uint qp[4];
#pragma unroll
  for (int qf = 0; qf < 4; ++qf) {
    int q = (wv + 8 * qf) * 16 + li;
    qp[qf] = ((uint)(q >> 5) << 10) + (((uint)(q >> 2) & 1u) << 9)
           + (((uint)(q & 31) >> 3) << 7) + ((uint)(q & 3) << 5) + ((uint)kg << 3);
  }
#pragma unroll
  for (int rf = 0; rf < 4; ++rf) {
#pragma unroll
    for (int qf = 0; qf < 4; ++qf) {
      union { u32x2 u; _Float16 h[4]; } dd;
      dd.u = *(const u32x2*)(smem + ((uint)rf << 14) + qp[qf]);
      part[rf * 4 + 0] = fmaf(acc[rf][qf][0], (float)dd.h[0], part[rf * 4 + 0]);
      part[rf * 4 + 1] = fmaf(acc[rf][qf][1], (float)dd.h[1], part[rf * 4 + 1]);
      part[rf * 4 + 2] = fmaf(acc[rf][qf][2], (float)dd.h[2], part[rf * 4 + 2]);
      part[rf * 4 + 3] = fmaf(acc[rf][qf][3], (float)dd.h[3], part[rf * 4 + 3]);
    }
  }

  __syncthreads();
#pragma unroll
  for (int x = 0; x < 16; ++x) {
    float v = part[x];
    v += __shfl_xor(v, 1);
    v += __shfl_xor(v, 2);
    v += __shfl_xor(v, 4);
    v += __shfl_xor(v, 8);
    part[x] = v;
  }
  float* rbuf = (float*)smem;
  if (li == 0) {
#pragma unroll
    for (int rf = 0; rf < 4; ++rf)
#pragma unroll
      for (int jj = 0; jj < 4; ++jj)
        rbuf[wv * 64 + rf * 16 + kg * 4 + jj] = part[rf * 4 + jj];
  }
  __syncthreads();
  if (t < BM) {
    float s = 0.0f;
#pragma unroll
    for (int w = 0; w < 8; ++w) s += rbuf[w * 64 + t];
    out[(size_t)n * MS + m0 + t] = s;
  }
}

// ---------------- ablation probes (write only to ws scratch) ----------------
// V=1: table+basis only.  V=2: GEMM only (R13 trip).  V=4: GEMM, 2 kblk per drain.
template<int V, int REP>
__launch_bounds__(512, 4)
__global__ void wfn_probe(const float* __restrict__ dv,
                          const uint* __restrict__ m2aG,
                          const uint* __restrict__ m2bG,
                          const float* __restrict__ alG,
                          const short* __restrict__ dmF,
                          float* __restrict__ scr) {
  __shared__ __align__(16) char smem[81920];
  const int t = threadIdx.x;
  const int bid = ((blockIdx.x & 7) << 7) + (blockIdx.x >> 3);
  const int n  = bid >> 6;
  const int m0 = (bid & 63) * BM;
  float live = 0.f;

  // deterministic LDS init (f16 1.0 pattern)
  for (int i = t; i < 81920 / 16; i += 512)
    ((u32x4*)smem)[i] = (u32x4){0x3C003C00u, 0x3C003C00u, 0x3C003C00u, 0x3C003C00u};
  __syncthreads();

  if constexpr (V == 1) {
    for (int rep = 0; rep < REP; ++rep) {
      build_table(smem, dv + (size_t)(n * MS + m0) * (NA * 3), t);
      __syncthreads();
      basis_phase(smem, m2aG[n * NP + t], m2bG[n * NP + t], alG[n * NP + t], t);
      __syncthreads();
    }
    live = (float)*(const _Float16*)(smem + ((uint)t << 1));
  } else {
    const int lane = t & 63, wv = t >> 6;
    const uint lane8 = (uint)lane << 3;
    const short* dmFn = dmF + (size_t)n * (32 * 16 * 512);
    f32x4 acc[4][4];
#pragma unroll
    for (int rf = 0; rf < 4; ++rf)
#pragma unroll
      for (int qf = 0; qf < 4; ++qf)
        acc[rf][qf] = (f32x4){0.f, 0.f, 0.f, 0.f};
    const short* bp0 = dmFn + ((size_t)((wv)      * 16) * 512) + lane * 8;
    const short* bp1 = dmFn + ((size_t)((wv + 8)  * 16) * 512) + lane * 8;
    const short* bp2 = dmFn + ((size_t)((wv + 16) * 16) * 512) + lane * 8;
    const short* bp3 = dmFn + ((size_t)((wv + 24) * 16) * 512) + lane * 8;
    const int kq0 = wv >> 1, kq1 = (wv + 8) >> 1, kq2 = (wv + 16) >> 1;
    const int kmaxw = (wv + 24) >> 1;

    for (int rep = 0; rep < REP; ++rep) {
      if constexpr (V == 2) {
        for (int kblk = 0; kblk <= kmaxw; ++kblk) {
          uint ak = lane8 + ((uint)kblk << 10);
          u32x2 l0, g0, l1, g1, l2, g2, l3, g3;
          ISSUE_TR(ak);
          FINISH_TRIP(kblk);
        }
      } else {   // V == 4: two kblk per lgkmcnt drain
        int kb = 0;
        while (kb <= kmaxw) {
          if (kb + 1 <= kmaxw) {
            uint akA = lane8 + ((uint)kb << 10);
            uint akB = akA + 1024u;
            u32x2 l0, g0, l1, g1, l2, g2, l3, g3;
            u32x2 r0, s0, r1, s1, r2, s2, r3, s3;
            ISSUE_TR(akA);
            ISSUE_TR_B(akB);
            f16x8 bf0, bf1, bf2, bf3;
            const bool c0 = kb <= kq0, c1 = kb <= kq1, c2 = kb <= kq2;
            if (c0) bf0 = *(const f16x8*)(bp0 + kb * 512);
            if (c1) bf1 = *(const f16x8*)(bp1 + kb * 512);
            if (c2) bf2 = *(const f16x8*)(bp2 + kb * 512);
            bf3 = *(const f16x8*)(bp3 + kb * 512);
            asm volatile("s_waitcnt lgkmcnt(0)");
            __builtin_amdgcn_sched_barrier(0);
            f16x8 af0 = mkfrag(l0, g0), af1 = mkfrag(l1, g1);
            f16x8 af2 = mkfrag(l2, g2), af3 = mkfrag(l3, g3);
            __builtin_amdgcn_s_setprio(1);
            if (c0) { acc[0][0]=MFMA16(af0,bf0,acc[0][0]); acc[1][0]=MFMA16(af1,bf0,acc[1][0]);
                      acc[2][0]=MFMA16(af2,bf0,acc[2][0]); acc[3][0]=MFMA16(af3,bf0,acc[3][0]); }
            if (c1) { acc[0][1]=MFMA16(af0,bf1,acc[0][1]); acc[1][1]=MFMA16(af1,bf1,acc[1][1]);
                      acc[2][1]=MFMA16(af2,bf1,acc[2][1]); acc[3][1]=MFMA16(af3,bf1,acc[3][1]); }
            if (c2) { acc[0][2]=MFMA16(af0,bf2,acc[0][2]); acc[1][2]=MFMA16(af1,bf2,acc[1][2]);
                      acc[2][2]=MFMA16(af2,bf2,acc[2][2]); acc[3][2]=MFMA16(af3,bf2,acc[3][2]); }
            acc[0][3]=MFMA16(af0,bf3,acc[0][3]); acc[1][3]=MFMA16(af1,bf3,acc[1][3]);
            acc[2][3]=MFMA16(af2,bf3,acc[2][3]); acc[3][3]=MFMA16(af3,bf3,acc[3][3]);
            // second sub-trip: fragments already drained, no extra wait
            const int kc = kb + 1;
            f16x8 e0, e1, e2, e3;
            const bool d0 = kc <= kq0, d1 = kc <= kq1, d2 = kc <= kq2;
            if (d0) e0 = *(const f16x8*)(bp0 + kc * 512);
            if (d1) e1 = *(const f16x8*)(bp1 + kc * 512);
            if (d2) e2 = *(const f16x8*)(bp2 + kc * 512);
            e3 = *(const f16x8*)(bp3 + kc * 512);
            f16x8 b0 = mkfrag(r0, s0), b1 = mkfrag(r1, s1);
            f16x8 b2 = mkfrag(r2, s2), b3 = mkfrag(r3, s3);
            if (d0) { acc[0][0]=MFMA16(b0,e0,acc[0][0]); acc[1][0]=MFMA16(b1,e0,acc[1][0]);
                      acc[2][0]=MFMA16(b2,e0,acc[2][0]); acc[3][0]=MFMA16(b3,e0,acc[3][0]); }
            if (d1) { acc[0][1]=MFMA16(b0,e1,acc[0][1]); acc[1][1]=MFMA16(b1,e1,acc[1][1]);
                      acc[2][1]=MFMA16(b2,e1,acc[2][1]); acc[3][1]=MFMA16(b3,e1,acc[3][1]); }
            if (d2) { acc[0][2]=MFMA16(b0,e2,acc[0][2]); acc[1][2]=MFMA16(b1,e2,acc[1][2]);
                      acc[2][2]=MFMA16(b2,e2,acc[2][2]); acc[3][2]=MFMA16(b3,e2,acc[3][2]); }
            acc[0][3]=MFMA16(b0,e3,acc[0][3]); acc[1][3]=MFMA16(b1,e3,acc[1][3]);
            acc[2][3]=MFMA16(b2,e3,acc[2][3]); acc[3][3]=MFMA16(b3,e3,acc[3][3]);
            __builtin_amdgcn_s_setprio(0);
            kb += 2;
          } else {
            uint ak = lane8 + ((uint)kb << 10);
            u32x2 l0, g0, l1, g1, l2, g2, l3, g3;
            ISSUE_TR(ak);
            FINISH_TRIP(kb);
            kb += 1;
          }
        }
      }
    }
    live = acc[0][0][0] + acc[1][1][1] + acc[2][2][2] + acc[3][3][3];
  }
  scr[(size_t)blockIdx.x * 512 + t] = live;
}

extern "C" void kernel_launch(void* const* d_in, const int* in_sizes, int n_in,
                              void* d_out, int out_size, void* d_ws, size_t ws_size,
                              hipStream_t stream) {
  const float* dv      = (const float*)d_in[0];
  const int*   centers = (const int*)d_in[1];
  const float* expg    = (const float*)d_in[2];
  const int*   sym     = (const int*)d_in[3];
  const float* dm      = (const float*)d_in[4];
  float* out = (float*)d_out;

  char* ws = (char*)d_ws;
  short* dmF    = (short*)(ws + WS_DMF_OFF);
  uint*  m2a    = (uint*)(ws + WS_M2A_OFF);
  uint*  m2b    = (uint*)(ws + WS_M2B_OFF);
  float* alphaS = (float*)(ws + WS_ALPH_OFF);

  dm_pack<<<dim3(16, NMOL), 256, 0, stream>>>(dm, dmF, centers, sym, expg,
                                              m2a, m2b, alphaS);
  wfn_fused8<<<dim3(NMOL * (MS / BM)), 512, 0, stream>>>(dv, m2a, m2b, alphaS, dmF, out);

  if (ws_size >= (48u << 20)) {   // diagnostic probes (scratch-only writes)
    float* scr1 = (float*)(ws + WS_SCR_OFF + (1u << 22));
    float* scr2 = (float*)(ws + WS_SCR_OFF + (2u << 22));
    float* scr4 = (float*)(ws + WS_SCR_OFF + (4u << 22));
    wfn_probe<1, 6><<<dim3(NMOL * (MS / BM)), 512, 0, stream>>>(dv, m2a, m2b, alphaS, dmF, scr1);
    wfn_probe<2, 4><<<dim3(NMOL * (MS / BM)), 512, 0, stream>>>(dv, m2a, m2b, alphaS, dmF, scr2);
    wfn_probe<4, 4><<<dim3(NMOL * (MS / BM)), 512, 0, stream>>>(dv, m2a, m2b, alphaS, dmF, scr4);
  }
}

// Round 15
// 106.298 us; speedup vs baseline: 1.8732x; 1.8732x over previous
//
#include <hip/hip_runtime.h>
#include <stdint.h>

#define NMOL 16
#define MS   4096
#define NA   32
#define NP   512
#define BM   64
#define TBL  65536u

typedef __attribute__((ext_vector_type(4))) float  f32x4;
typedef __attribute__((ext_vector_type(4))) unsigned int u32x4;
typedef __attribute__((ext_vector_type(2))) unsigned int u32x2;
typedef __attribute__((ext_vector_type(8))) short  s16x8;
typedef __attribute__((ext_vector_type(8))) _Float16 f16x8;
typedef unsigned int uint;
typedef unsigned short ushort;

// ws layout
#define WS_DMF_OFF   0u
#define WS_DMF_SZ    (16u*512u*512u*2u)
#define WS_M2A_OFF   (WS_DMF_OFF + WS_DMF_SZ)
#define WS_M2A_SZ    (16u*512u*4u)
#define WS_M2B_OFF   (WS_M2A_OFF + WS_M2A_SZ)
#define WS_M2B_SZ    (16u*512u*4u)
#define WS_ALPH_OFF  (WS_M2B_OFF + WS_M2B_SZ)
#define WS_SCR_OFF   (16u << 20)

// WFN symmetry table packed px | py<<4 | pz<<8
__device__ __constant__ uint c_pw[20] = {
  0x000,
  0x001, 0x010, 0x100,
  0x002, 0x020, 0x200, 0x011, 0x101, 0x110,
  0x003, 0x030, 0x300, 0x012, 0x102, 0x120, 0x021, 0x201, 0x210, 0x111
};

__device__ __forceinline__ float cvt16lo(uint u) {
  float r; asm("v_cvt_f32_f16 %0, %1" : "=v"(r) : "v"(u)); return r;
}
__device__ __forceinline__ float cvt16hi(uint u) {
  uint s = u >> 16; float r; asm("v_cvt_f32_f16 %0, %1" : "=v"(r) : "v"(s)); return r;
}
__device__ __forceinline__ uint pkmul(uint a, uint b) {
  uint r; asm("v_pk_mul_f16 %0, %1, %2" : "=v"(r) : "v"(a), "v"(b)); return r;
}
__device__ __forceinline__ uint f2h2(float a, float b) {
  union { __fp16 __attribute__((ext_vector_type(2))) h; uint u; } x;
  x.h = __builtin_amdgcn_cvt_pkrtz(a, b);
  return x.u;
}
__device__ __forceinline__ short f2hs(float f) {
  _Float16 h = (_Float16)f;
  union { _Float16 h; short s; } x; x.h = h; return x.s;
}
__device__ __forceinline__ f16x8 mkfrag(u32x2 lo, u32x2 hi) {
  union { uint u[4]; f16x8 v; } x;
  x.u[0] = lo[0]; x.u[1] = lo[1]; x.u[2] = hi[0]; x.u[3] = hi[1];
  return x.v;
}

// ---- dm fp32 [n][p][q] -> W' = symmetrized upper-tri, f16 fragment-packed.
// Meta h now encodes the axis-major table: h = ax*4096 + c*8 (bank-spread by c).
__global__ void dm_pack(const float* __restrict__ dm, short* __restrict__ dmF,
                        const int* __restrict__ centers, const int* __restrict__ sym,
                        const float* __restrict__ expg,
                        uint* __restrict__ m2a, uint* __restrict__ m2b,
                        float* __restrict__ alphaS) {
  __shared__ float tile[NP * 33];
  const int Qp = blockIdx.x, n = blockIdx.y;
  const int t = threadIdx.x;
  const float* base = dm + (size_t)n * NP * NP;
  const float* src  = base + Qp * 32;
#pragma unroll
  for (int i = 0; i < 64; ++i) {
    int e = t + 256 * i;
    int p = e >> 5, c = e & 31;
    tile[p * 33 + c] = src[(size_t)p * NP + c];
  }
  if (n == 0) {
#pragma unroll
    for (int kk = 0; kk < 2; ++kk) {
      int i = Qp * 512 + t + 256 * kk;
      int craw = centers[i], s = sym[i];
      bool valid = (craw >= 0);
      uint c = (uint)((valid ? craw : 0) & (NA - 1));
      int si = valid ? s : 0;
      si = (si >= 0 && si < 20) ? si : 0;
      uint pw = c_pw[si];
      uint d = (pw & 15u) + ((pw >> 4) & 15u) + ((pw >> 8) & 15u);
      uint h[3]; int k = 0;
#pragma unroll
      for (uint ax = 0; ax < 3; ++ax) {
        uint e2 = (pw >> (4 * ax)) & 15u;
        for (uint r = 0; r < e2; ++r) if (k < 3) h[k++] = ax * 4096u + c * 8u;
      }
      while (k < 3) h[k++] = c * 8u;          // pad: x-row of c (unused when d small)
      m2a[i] = h[0] | (h[1] << 16);
      m2b[i] = h[2] | (d << 14) | (c << 16);
      alphaS[i] = (valid ? -expg[i] : -1e5f) * 1.44269504088896f;
    }
  }
  __syncthreads();
#pragma unroll
  for (int it = 0; it < 8; ++it) {
    int v = t + 256 * it;
    int qq = v >> 10, vv = v & 1023;
    int kblk = vv >> 6, l = vv & 63;
    int p0 = kblk * 32 + ((l >> 4) << 3);
    int col = l & 15;
    int q = (Qp * 2 + qq) * 16 + col;
    f32x4 r0 = *(const f32x4*)(base + (size_t)q * NP + p0);
    f32x4 r1 = *(const f32x4*)(base + (size_t)q * NP + p0 + 4);
    s16x8 o;
#pragma unroll
    for (int j = 0; j < 8; ++j) {
      int p = p0 + j;
      float tpq = tile[p * 33 + qq * 16 + col];
      float rv = (j < 4) ? r0[j] : r1[j - 4];
      float w = (p < q) ? (tpq + rv) : ((p == q) ? tpq : 0.0f);
      o[j] = f2hs(w);
    }
    short* dst = dmF + ((size_t)(n * 32 + Qp * 2 + qq) * 16) * 512;
    *(s16x8*)(dst + (size_t)vv * 8) = o;
  }
}

#define MFMA16(a, b, c) __builtin_amdgcn_mfma_f32_16x16x32_f16(a, b, c, 0, 0, 0)

#define ISSUE_TR(AK) \
  asm volatile("ds_read_b64_tr_b16 %0, %1 offset:0"     : "=v"(l0) : "v"(AK)); \
  asm volatile("ds_read_b64_tr_b16 %0, %1 offset:512"   : "=v"(g0) : "v"(AK)); \
  asm volatile("ds_read_b64_tr_b16 %0, %1 offset:16384" : "=v"(l1) : "v"(AK)); \
  asm volatile("ds_read_b64_tr_b16 %0, %1 offset:16896" : "=v"(g1) : "v"(AK)); \
  asm volatile("ds_read_b64_tr_b16 %0, %1 offset:32768" : "=v"(l2) : "v"(AK)); \
  asm volatile("ds_read_b64_tr_b16 %0, %1 offset:33280" : "=v"(g2) : "v"(AK)); \
  asm volatile("ds_read_b64_tr_b16 %0, %1 offset:49152" : "=v"(l3) : "v"(AK)); \
  asm volatile("ds_read_b64_tr_b16 %0, %1 offset:49664" : "=v"(g3) : "v"(AK));

// R8-proven trip: full lgkmcnt(0) drain before any fragment use (counted-lgkm
// ladders with tr-reads are UNVERIFIED and failed in R10 — do not reintroduce).
#define FINISH_TRIP(KBLK) do { \
  f16x8 bf0, bf1, bf2, bf3; \
  const bool c0 = (KBLK) <= kq0, c1 = (KBLK) <= kq1, c2 = (KBLK) <= kq2; \
  if (c0) bf0 = *(const f16x8*)(bp0 + (KBLK) * 512); \
  if (c1) bf1 = *(const f16x8*)(bp1 + (KBLK) * 512); \
  if (c2) bf2 = *(const f16x8*)(bp2 + (KBLK) * 512); \
  bf3 = *(const f16x8*)(bp3 + (KBLK) * 512); \
  asm volatile("s_waitcnt lgkmcnt(0)"); \
  __builtin_amdgcn_sched_barrier(0); \
  f16x8 af0 = mkfrag(l0, g0), af1 = mkfrag(l1, g1); \
  f16x8 af2 = mkfrag(l2, g2), af3 = mkfrag(l3, g3); \
  __builtin_amdgcn_s_setprio(1); \
  if (c0) { acc[0][0]=MFMA16(af0,bf0,acc[0][0]); acc[1][0]=MFMA16(af1,bf0,acc[1][0]); \
            acc[2][0]=MFMA16(af2,bf0,acc[2][0]); acc[3][0]=MFMA16(af3,bf0,acc[3][0]); } \
  if (c1) { acc[0][1]=MFMA16(af0,bf1,acc[0][1]); acc[1][1]=MFMA16(af1,bf1,acc[1][1]); \
            acc[2][1]=MFMA16(af2,bf1,acc[2][1]); acc[3][1]=MFMA16(af3,bf1,acc[3][1]); } \
  if (c2) { acc[0][2]=MFMA16(af0,bf2,acc[0][2]); acc[1][2]=MFMA16(af1,bf2,acc[1][2]); \
            acc[2][2]=MFMA16(af2,bf2,acc[2][2]); acc[3][2]=MFMA16(af3,bf2,acc[3][2]); } \
  acc[0][3]=MFMA16(af0,bf3,acc[0][3]); acc[1][3]=MFMA16(af1,bf3,acc[1][3]); \
  acc[2][3]=MFMA16(af2,bf3,acc[2][3]); acc[3][3]=MFMA16(af3,bf3,acc[3][3]); \
  __builtin_amdgcn_s_setprio(0); \
} while (0)

// table layout (conflict-free): [ax(4)][chunk(16) of 4 f16][c(32)] × 8B, 16 KB at TBL.
// addr = TBL + ax*4096 + (m>>2)*256 + c*8 + (m&3)*2 ; bank-pair = c&15 -> 2-way max.
__device__ __forceinline__ void build_table(char* smem, const float* dvg, int t) {
#pragma unroll
  for (int k = 0; k < 4; ++k) {
    int idx = t + 512 * k;
    int m = idx >> 5, c = idx & 31;
    const float* p = dvg + (m * NA + c) * 3;
    float x = p[0], y = p[1], z = p[2];
    float r2 = fmaf(x, x, fmaf(y, y, z * z));
    uint base = TBL + ((uint)(m >> 2) << 8) + (uint)c * 8u + (uint)((m & 3) << 1);
    *(_Float16*)(smem + base)         = (_Float16)x;
    *(_Float16*)(smem + base + 4096)  = (_Float16)y;
    *(_Float16*)(smem + base + 8192)  = (_Float16)z;
    *(_Float16*)(smem + base + 12288) = (_Float16)r2;
  }
}

__device__ __forceinline__ void basis_phase(char* smem, uint ma, uint mb, float al, int p) {
  const uint alp = f2h2(al, al);
  const uint h0 = ma & 0xFFFFu, h1 = ma >> 16;
  const uint h2v = mb & 0x3FFFu;
  const uint d  = (mb >> 14) & 3u;
  const uint c  = mb >> 16;
  const uint rh = 12288u + c * 8u;
  const bool ge2 = (d >= 2), eq3 = (d == 3), eq0 = (d == 0);
  const uint wbase = ((uint)(p >> 5) << 10) + (((uint)(p >> 2) & 1u) << 9)
                   + ((((uint)p & 31u) >> 3) << 7) + (((uint)p & 3u) << 5);
#pragma unroll
  for (int j = 0; j < 8; ++j) {
    uint o = (uint)j << 9;               // chunk 2j at +0, chunk 2j+1 at +256
    u32x2 qra = *(const u32x2*)(smem + TBL + rh + o);
    u32x2 qrb = *(const u32x2*)(smem + TBL + rh + o + 256);
    u32x2 q0a, q0b, q1a, q1b, q2a, q2b;
    if (!eq0) { q0a = *(const u32x2*)(smem + TBL + h0 + o);
                q0b = *(const u32x2*)(smem + TBL + h0 + o + 256); }
    if (ge2)  { q1a = *(const u32x2*)(smem + TBL + h1 + o);
                q1b = *(const u32x2*)(smem + TBL + h1 + o + 256); }
    if (eq3)  { q2a = *(const u32x2*)(smem + TBL + h2v + o);
                q2b = *(const u32x2*)(smem + TBL + h2v + o + 256); }
    uint res[4];
#pragma unroll
    for (int w = 0; w < 4; ++w) {
      uint mq = eq0 ? 0x3C003C00u : ((w < 2) ? q0a[w] : q0b[w - 2]);
      if (ge2) mq = pkmul(mq, (w < 2) ? q1a[w] : q1b[w - 2]);
      if (eq3) mq = pkmul(mq, (w < 2) ? q2a[w] : q2b[w - 2]);
      uint ap = pkmul(alp, (w < 2) ? qra[w] : qrb[w - 2]);
      float a0 = cvt16lo(ap), a1 = cvt16hi(ap);
      float e0, e1;
      asm("v_exp_f32 %0, %1" : "=v"(e0) : "v"(a0));
      asm("v_exp_f32 %0, %1" : "=v"(e1) : "v"(a1));
      res[w] = pkmul(mq, f2h2(e0, e1));
    }
    *(u32x4*)(smem + wbase + ((uint)(j >> 1) << 14) + ((uint)(j & 1) << 4))
        = *(u32x4*)res;
  }
}

// ---------------- real fused kernel (R13 structure + conflict-free table) --------
__launch_bounds__(512, 4)
__global__ void wfn_fused8(const float* __restrict__ dv,
                           const uint* __restrict__ m2aG,
                           const uint* __restrict__ m2bG,
                           const float* __restrict__ alG,
                           const short* __restrict__ dmF,
                           float* __restrict__ out) {
  __shared__ __align__(16) char smem[81920];
  const int t = threadIdx.x;
  const int bid = ((blockIdx.x & 7) << 7) + (blockIdx.x >> 3);
  const int n  = bid >> 6;
  const int m0 = (bid & 63) * BM;

  build_table(smem, dv + (size_t)(n * MS + m0) * (NA * 3), t);
  __syncthreads();
  basis_phase(smem, m2aG[n * NP + t], m2bG[n * NP + t], alG[n * NP + t], t);
  __syncthreads();

  const int lane = t & 63, wv = t >> 6, li = lane & 15, kg = lane >> 4;
  const uint lane8 = (uint)lane << 3;
  const short* dmFn = dmF + (size_t)n * (32 * 16 * 512);

  f32x4 acc[4][4];
#pragma unroll
  for (int rf = 0; rf < 4; ++rf)
#pragma unroll
    for (int qf = 0; qf < 4; ++qf)
      acc[rf][qf] = (f32x4){0.f, 0.f, 0.f, 0.f};

  const short* bp0 = dmFn + ((size_t)((wv)      * 16) * 512) + lane * 8;
  const short* bp1 = dmFn + ((size_t)((wv + 8)  * 16) * 512) + lane * 8;
  const short* bp2 = dmFn + ((size_t)((wv + 16) * 16) * 512) + lane * 8;
  const short* bp3 = dmFn + ((size_t)((wv + 24) * 16) * 512) + lane * 8;
  const int kq0 = wv >> 1, kq1 = (wv + 8) >> 1, kq2 = (wv + 16) >> 1;
  const int kmaxw = (wv + 24) >> 1;

  for (int kblk = 0; kblk <= kmaxw; ++kblk) {
    uint ak = lane8 + ((uint)kblk << 10);
    u32x2 l0, g0, l1, g1, l2, g2, l3, g3;
    ISSUE_TR(ak);
    FINISH_TRIP(kblk);
  }

  float part[16];
#pragma unroll
  for (int x = 0; x < 16; ++x) part[x] = 0.0f;
  uint qp[4];
#pragma unroll
  for (int qf = 0; qf < 4; ++qf) {
    int q = (wv + 8 * qf) * 16 + li;
    qp[qf] = ((uint)(q >> 5) << 10) + (((uint)(q >> 2) & 1u) << 9)
           + (((uint)(q & 31) >> 3) << 7) + ((uint)(q & 3) << 5) + ((uint)kg << 3);
  }
#pragma unroll
  for (int rf = 0; rf < 4; ++rf) {
#pragma unroll
    for (int qf = 0; qf < 4; ++qf) {
      union { u32x2 u; _Float16 h[4]; } dd;
      dd.u = *(const u32x2*)(smem + ((uint)rf << 14) + qp[qf]);
      part[rf * 4 + 0] = fmaf(acc[rf][qf][0], (float)dd.h[0], part[rf * 4 + 0]);
      part[rf * 4 + 1] = fmaf(acc[rf][qf][1], (float)dd.h[1], part[rf * 4 + 1]);
      part[rf * 4 + 2] = fmaf(acc[rf][qf][2], (float)dd.h[2], part[rf * 4 + 2]);
      part[rf * 4 + 3] = fmaf(acc[rf][qf][3], (float)dd.h[3], part[rf * 4 + 3]);
    }
  }

  __syncthreads();
#pragma unroll
  for (int x = 0; x < 16; ++x) {
    float v = part[x];
    v += __shfl_xor(v, 1);
    v += __shfl_xor(v, 2);
    v += __shfl_xor(v, 4);
    v += __shfl_xor(v, 8);
    part[x] = v;
  }
  float* rbuf = (float*)smem;
  if (li == 0) {
#pragma unroll
    for (int rf = 0; rf < 4; ++rf)
#pragma unroll
      for (int jj = 0; jj < 4; ++jj)
        rbuf[wv * 64 + rf * 16 + kg * 4 + jj] = part[rf * 4 + jj];
  }
  __syncthreads();
  if (t < BM) {
    float s = 0.0f;
#pragma unroll
    for (int w = 0; w < 8; ++w) s += rbuf[w * 64 + t];
    out[(size_t)n * MS + m0 + t] = s;
  }
}

// ---------------- ablation probe #2: GEMM phase only, REP=6 ----------------
__launch_bounds__(512, 4)
__global__ void wfn_probe_gemm(const short* __restrict__ dmF,
                               float* __restrict__ scr) {
  __shared__ __align__(16) char smem[81920];
  const int t = threadIdx.x;
  const int bid = ((blockIdx.x & 7) << 7) + (blockIdx.x >> 3);
  const int n  = bid >> 6;

  for (int i = t; i < 81920 / 16; i += 512)
    ((u32x4*)smem)[i] = (u32x4){0x3C003C00u, 0x3C003C00u, 0x3C003C00u, 0x3C003C00u};
  __syncthreads();

  const int lane = t & 63, wv = t >> 6;
  const uint lane8 = (uint)lane << 3;
  const short* dmFn = dmF + (size_t)n * (32 * 16 * 512);
  f32x4 acc[4][4];
#pragma unroll
  for (int rf = 0; rf < 4; ++rf)
#pragma unroll
    for (int qf = 0; qf < 4; ++qf)
      acc[rf][qf] = (f32x4){0.f, 0.f, 0.f, 0.f};
  const short* bp0 = dmFn + ((size_t)((wv)      * 16) * 512) + lane * 8;
  const short* bp1 = dmFn + ((size_t)((wv + 8)  * 16) * 512) + lane * 8;
  const short* bp2 = dmFn + ((size_t)((wv + 16) * 16) * 512) + lane * 8;
  const short* bp3 = dmFn + ((size_t)((wv + 24) * 16) * 512) + lane * 8;
  const int kq0 = wv >> 1, kq1 = (wv + 8) >> 1, kq2 = (wv + 16) >> 1;
  const int kmaxw = (wv + 24) >> 1;

  for (int rep = 0; rep < 6; ++rep) {
    for (int kblk = 0; kblk <= kmaxw; ++kblk) {
      uint ak = lane8 + ((uint)kblk << 10);
      u32x2 l0, g0, l1, g1, l2, g2, l3, g3;
      ISSUE_TR(ak);
      FINISH_TRIP(kblk);
    }
  }
  float live = acc[0][0][0] + acc[1][1][1] + acc[2][2][2] + acc[3][3][3];
  scr[(size_t)blockIdx.x * 512 + t] = live;
}

extern "C" void kernel_launch(void* const* d_in, const int* in_sizes, int n_in,
                              void* d_out, int out_size, void* d_ws, size_t ws_size,
                              hipStream_t stream) {
  const float* dv      = (const float*)d_in[0];
  const int*   centers = (const int*)d_in[1];
  const float* expg    = (const float*)d_in[2];
  const int*   sym     = (const int*)d_in[3];
  const float* dm      = (const float*)d_in[4];
  float* out = (float*)d_out;

  char* ws = (char*)d_ws;
  short* dmF    = (short*)(ws + WS_DMF_OFF);
  uint*  m2a    = (uint*)(ws + WS_M2A_OFF);
  uint*  m2b    = (uint*)(ws + WS_M2B_OFF);
  float* alphaS = (float*)(ws + WS_ALPH_OFF);

  dm_pack<<<dim3(16, NMOL), 256, 0, stream>>>(dm, dmF, centers, sym, expg,
                                              m2a, m2b, alphaS);
  wfn_fused8<<<dim3(NMOL * (MS / BM)), 512, 0, stream>>>(dv, m2a, m2b, alphaS, dmF, out);

  if (ws_size >= (32u << 20)) {   // diagnostic probe (scratch-only writes)
    float* scr = (float*)(ws + WS_SCR_OFF);
    wfn_probe_gemm<<<dim3(NMOL * (MS / BM)), 512, 0, stream>>>(dmF, scr);
  }
}

// Round 16
// 49.263 us; speedup vs baseline: 4.0420x; 2.1578x over previous
//
#include <hip/hip_runtime.h>
#include <stdint.h>

#define NMOL 16
#define MS   4096
#define NA   32
#define NP   512
#define BM   64
#define TBL  65536u

typedef __attribute__((ext_vector_type(4))) float  f32x4;
typedef __attribute__((ext_vector_type(4))) unsigned int u32x4;
typedef __attribute__((ext_vector_type(2))) unsigned int u32x2;
typedef __attribute__((ext_vector_type(8))) short  s16x8;
typedef __attribute__((ext_vector_type(8))) _Float16 f16x8;
typedef unsigned int uint;
typedef unsigned short ushort;

// ws layout
#define WS_DMF_OFF   0u
#define WS_DMF_SZ    (16u*512u*512u*2u)
#define WS_M2A_OFF   (WS_DMF_OFF + WS_DMF_SZ)
#define WS_M2A_SZ    (16u*512u*4u)
#define WS_M2B_OFF   (WS_M2A_OFF + WS_M2A_SZ)
#define WS_M2B_SZ    (16u*512u*4u)
#define WS_ALPH_OFF  (WS_M2B_OFF + WS_M2B_SZ)

// WFN symmetry table packed px | py<<4 | pz<<8
__device__ __constant__ uint c_pw[20] = {
  0x000,
  0x001, 0x010, 0x100,
  0x002, 0x020, 0x200, 0x011, 0x101, 0x110,
  0x003, 0x030, 0x300, 0x012, 0x102, 0x120, 0x021, 0x201, 0x210, 0x111
};

__device__ __forceinline__ float cvt16lo(uint u) {
  float r; asm("v_cvt_f32_f16 %0, %1" : "=v"(r) : "v"(u)); return r;
}
__device__ __forceinline__ float cvt16hi(uint u) {
  uint s = u >> 16; float r; asm("v_cvt_f32_f16 %0, %1" : "=v"(r) : "v"(s)); return r;
}
__device__ __forceinline__ uint pkmul(uint a, uint b) {
  uint r; asm("v_pk_mul_f16 %0, %1, %2" : "=v"(r) : "v"(a), "v"(b)); return r;
}
__device__ __forceinline__ uint f2h2(float a, float b) {
  union { __fp16 __attribute__((ext_vector_type(2))) h; uint u; } x;
  x.h = __builtin_amdgcn_cvt_pkrtz(a, b);
  return x.u;
}
__device__ __forceinline__ short f2hs(float f) {
  _Float16 h = (_Float16)f;
  union { _Float16 h; short s; } x; x.h = h; return x.s;
}
__device__ __forceinline__ f16x8 mkfrag(u32x2 lo, u32x2 hi) {
  union { uint u[4]; f16x8 v; } x;
  x.u[0] = lo[0]; x.u[1] = lo[1]; x.u[2] = hi[0]; x.u[3] = hi[1];
  return x.v;
}

// ---- dm fp32 [n][p][q] -> W' = symmetrized upper-tri, f16 fragment-packed.
// Meta h encodes the axis-major table: h = ax*4096 + c*8 (bank-spread by c).
__global__ void dm_pack(const float* __restrict__ dm, short* __restrict__ dmF,
                        const int* __restrict__ centers, const int* __restrict__ sym,
                        const float* __restrict__ expg,
                        uint* __restrict__ m2a, uint* __restrict__ m2b,
                        float* __restrict__ alphaS) {
  __shared__ float tile[NP * 33];
  const int Qp = blockIdx.x, n = blockIdx.y;
  const int t = threadIdx.x;
  const float* base = dm + (size_t)n * NP * NP;
  const float* src  = base + Qp * 32;
#pragma unroll
  for (int i = 0; i < 64; ++i) {
    int e = t + 256 * i;
    int p = e >> 5, c = e & 31;
    tile[p * 33 + c] = src[(size_t)p * NP + c];
  }
  if (n == 0) {
#pragma unroll
    for (int kk = 0; kk < 2; ++kk) {
      int i = Qp * 512 + t + 256 * kk;
      int craw = centers[i], s = sym[i];
      bool valid = (craw >= 0);
      uint c = (uint)((valid ? craw : 0) & (NA - 1));
      int si = valid ? s : 0;
      si = (si >= 0 && si < 20) ? si : 0;
      uint pw = c_pw[si];
      uint d = (pw & 15u) + ((pw >> 4) & 15u) + ((pw >> 8) & 15u);
      uint h[3]; int k = 0;
#pragma unroll
      for (uint ax = 0; ax < 3; ++ax) {
        uint e2 = (pw >> (4 * ax)) & 15u;
        for (uint r = 0; r < e2; ++r) if (k < 3) h[k++] = ax * 4096u + c * 8u;
      }
      while (k < 3) h[k++] = c * 8u;          // pad row (unused when d small)
      m2a[i] = h[0] | (h[1] << 16);
      m2b[i] = h[2] | (d << 14) | (c << 16);
      alphaS[i] = (valid ? -expg[i] : -1e5f) * 1.44269504088896f;
    }
  }
  __syncthreads();
#pragma unroll
  for (int it = 0; it < 8; ++it) {
    int v = t + 256 * it;
    int qq = v >> 10, vv = v & 1023;
    int kblk = vv >> 6, l = vv & 63;
    int p0 = kblk * 32 + ((l >> 4) << 3);
    int col = l & 15;
    int q = (Qp * 2 + qq) * 16 + col;
    f32x4 r0 = *(const f32x4*)(base + (size_t)q * NP + p0);
    f32x4 r1 = *(const f32x4*)(base + (size_t)q * NP + p0 + 4);
    s16x8 o;
#pragma unroll
    for (int j = 0; j < 8; ++j) {
      int p = p0 + j;
      float tpq = tile[p * 33 + qq * 16 + col];
      float rv = (j < 4) ? r0[j] : r1[j - 4];
      float w = (p < q) ? (tpq + rv) : ((p == q) ? tpq : 0.0f);
      o[j] = f2hs(w);
    }
    short* dst = dmF + ((size_t)(n * 32 + Qp * 2 + qq) * 16) * 512;
    *(s16x8*)(dst + (size_t)vv * 8) = o;
  }
}

#define MFMA16(a, b, c) __builtin_amdgcn_mfma_f32_16x16x32_f16(a, b, c, 0, 0, 0)

#define ISSUE_TR(AK) \
  asm volatile("ds_read_b64_tr_b16 %0, %1 offset:0"     : "=v"(l0) : "v"(AK)); \
  asm volatile("ds_read_b64_tr_b16 %0, %1 offset:512"   : "=v"(g0) : "v"(AK)); \
  asm volatile("ds_read_b64_tr_b16 %0, %1 offset:16384" : "=v"(l1) : "v"(AK)); \
  asm volatile("ds_read_b64_tr_b16 %0, %1 offset:16896" : "=v"(g1) : "v"(AK)); \
  asm volatile("ds_read_b64_tr_b16 %0, %1 offset:32768" : "=v"(l2) : "v"(AK)); \
  asm volatile("ds_read_b64_tr_b16 %0, %1 offset:33280" : "=v"(g2) : "v"(AK)); \
  asm volatile("ds_read_b64_tr_b16 %0, %1 offset:49152" : "=v"(l3) : "v"(AK)); \
  asm volatile("ds_read_b64_tr_b16 %0, %1 offset:49664" : "=v"(g3) : "v"(AK));

// One trip. B loads issued FIRST (L2 latency gets a head start under the
// tr-read issue+drain window). Full lgkmcnt(0) drain before fragment use
// (counted-lgkm ladders with tr-reads are UNVERIFIED and failed in R10).
#define GEMM_TRIP(KBLK) do { \
  f16x8 bf0, bf1, bf2, bf3; \
  const bool c0 = (KBLK) <= kq0, c1 = (KBLK) <= kq1, c2 = (KBLK) <= kq2; \
  if (c0) bf0 = *(const f16x8*)(bp0 + (KBLK) * 512); \
  if (c1) bf1 = *(const f16x8*)(bp1 + (KBLK) * 512); \
  if (c2) bf2 = *(const f16x8*)(bp2 + (KBLK) * 512); \
  bf3 = *(const f16x8*)(bp3 + (KBLK) * 512); \
  uint ak = lane8 + ((uint)(KBLK) << 10); \
  u32x2 l0, g0, l1, g1, l2, g2, l3, g3; \
  ISSUE_TR(ak); \
  asm volatile("s_waitcnt lgkmcnt(0)"); \
  __builtin_amdgcn_sched_barrier(0); \
  f16x8 af0 = mkfrag(l0, g0), af1 = mkfrag(l1, g1); \
  f16x8 af2 = mkfrag(l2, g2), af3 = mkfrag(l3, g3); \
  __builtin_amdgcn_s_setprio(1); \
  if (c0) { acc[0][0]=MFMA16(af0,bf0,acc[0][0]); acc[1][0]=MFMA16(af1,bf0,acc[1][0]); \
            acc[2][0]=MFMA16(af2,bf0,acc[2][0]); acc[3][0]=MFMA16(af3,bf0,acc[3][0]); } \
  if (c1) { acc[0][1]=MFMA16(af0,bf1,acc[0][1]); acc[1][1]=MFMA16(af1,bf1,acc[1][1]); \
            acc[2][1]=MFMA16(af2,bf1,acc[2][1]); acc[3][1]=MFMA16(af3,bf1,acc[3][1]); } \
  if (c2) { acc[0][2]=MFMA16(af0,bf2,acc[0][2]); acc[1][2]=MFMA16(af1,bf2,acc[1][2]); \
            acc[2][2]=MFMA16(af2,bf2,acc[2][2]); acc[3][2]=MFMA16(af3,bf2,acc[3][2]); } \
  acc[0][3]=MFMA16(af0,bf3,acc[0][3]); acc[1][3]=MFMA16(af1,bf3,acc[1][3]); \
  acc[2][3]=MFMA16(af2,bf3,acc[2][3]); acc[3][3]=MFMA16(af3,bf3,acc[3][3]); \
  __builtin_amdgcn_s_setprio(0); \
} while (0)

// table layout (conflict-free): [ax(4)][chunk(16) of 4 f16][c(32)] × 8B, 16 KB at TBL.
// addr = TBL + ax*4096 + (m>>2)*256 + c*8 + (m&3)*2 ; bank-pair = c&15 -> 2-way max.
__device__ __forceinline__ void build_table(char* smem, const float* dvg, int t) {
#pragma unroll
  for (int k = 0; k < 4; ++k) {
    int idx = t + 512 * k;
    int m = idx >> 5, c = idx & 31;
    const float* p = dvg + (m * NA + c) * 3;
    float x = p[0], y = p[1], z = p[2];
    float r2 = fmaf(x, x, fmaf(y, y, z * z));
    uint base = TBL + ((uint)(m >> 2) << 8) + (uint)c * 8u + (uint)((m & 3) << 1);
    *(_Float16*)(smem + base)         = (_Float16)x;
    *(_Float16*)(smem + base + 4096)  = (_Float16)y;
    *(_Float16*)(smem + base + 8192)  = (_Float16)z;
    *(_Float16*)(smem + base + 12288) = (_Float16)r2;
  }
}

__device__ __forceinline__ void basis_phase(char* smem, uint ma, uint mb, float al, int p) {
  const uint alp = f2h2(al, al);
  const uint h0 = ma & 0xFFFFu, h1 = ma >> 16;
  const uint h2v = mb & 0x3FFFu;
  const uint d  = (mb >> 14) & 3u;
  const uint c  = mb >> 16;
  const uint rh = 12288u + c * 8u;
  const bool ge2 = (d >= 2), eq3 = (d == 3), eq0 = (d == 0);
  const uint wbase = ((uint)(p >> 5) << 10) + (((uint)(p >> 2) & 1u) << 9)
                   + ((((uint)p & 31u) >> 3) << 7) + (((uint)p & 3u) << 5);
#pragma unroll
  for (int j = 0; j < 8; ++j) {
    uint o = (uint)j << 9;               // chunk 2j at +0, chunk 2j+1 at +256
    u32x2 qra = *(const u32x2*)(smem + TBL + rh + o);
    u32x2 qrb = *(const u32x2*)(smem + TBL + rh + o + 256);
    u32x2 q0a, q0b, q1a, q1b, q2a, q2b;
    if (!eq0) { q0a = *(const u32x2*)(smem + TBL + h0 + o);
                q0b = *(const u32x2*)(smem + TBL + h0 + o + 256); }
    if (ge2)  { q1a = *(const u32x2*)(smem + TBL + h1 + o);
                q1b = *(const u32x2*)(smem + TBL + h1 + o + 256); }
    if (eq3)  { q2a = *(const u32x2*)(smem + TBL + h2v + o);
                q2b = *(const u32x2*)(smem + TBL + h2v + o + 256); }
    uint res[4];
#pragma unroll
    for (int w = 0; w < 4; ++w) {
      uint mq = eq0 ? 0x3C003C00u : ((w < 2) ? q0a[w] : q0b[w - 2]);
      if (ge2) mq = pkmul(mq, (w < 2) ? q1a[w] : q1b[w - 2]);
      if (eq3) mq = pkmul(mq, (w < 2) ? q2a[w] : q2b[w - 2]);
      uint ap = pkmul(alp, (w < 2) ? qra[w] : qrb[w - 2]);
      float a0 = cvt16lo(ap), a1 = cvt16hi(ap);
      float e0, e1;
      asm("v_exp_f32 %0, %1" : "=v"(e0) : "v"(a0));
      asm("v_exp_f32 %0, %1" : "=v"(e1) : "v"(a1));
      res[w] = pkmul(mq, f2h2(e0, e1));
    }
    *(u32x4*)(smem + wbase + ((uint)(j >> 1) << 14) + ((uint)(j & 1) << 4))
        = *(u32x4*)res;
  }
}

// ---------------- fused basis + triangular GEMM + quadratic-form ----------------
// LDS map (81920 B exact -> 2 blocks/CU):
//   [0, 65536)      basis f16 in [4p][16m] tiles, order [mblk(4)][kblk(16)][par(2)][kg(4)]
//   [65536, 81920)  comp table f16 axis-major (conflict-free, see build_table)
__launch_bounds__(512, 4)
__global__ void wfn_fused8(const float* __restrict__ dv,
                           const uint* __restrict__ m2aG,
                           const uint* __restrict__ m2bG,
                           const float* __restrict__ alG,
                           const short* __restrict__ dmF,
                           float* __restrict__ out) {
  __shared__ __align__(16) char smem[81920];
  const int t = threadIdx.x;
  const int bid = ((blockIdx.x & 7) << 7) + (blockIdx.x >> 3);   // XCD swizzle
  const int n  = bid >> 6;
  const int m0 = (bid & 63) * BM;

  build_table(smem, dv + (size_t)(n * MS + m0) * (NA * 3), t);
  __syncthreads();
  basis_phase(smem, m2aG[n * NP + t], m2bG[n * NP + t], alG[n * NP + t], t);
  __syncthreads();

  const int lane = t & 63, wv = t >> 6, li = lane & 15, kg = lane >> 4;
  const uint lane8 = (uint)lane << 3;
  const short* dmFn = dmF + (size_t)n * (32 * 16 * 512);

  f32x4 acc[4][4];
#pragma unroll
  for (int rf = 0; rf < 4; ++rf)
#pragma unroll
    for (int qf = 0; qf < 4; ++qf)
      acc[rf][qf] = (f32x4){0.f, 0.f, 0.f, 0.f};

  // interleaved q assignment balances triangular work: Qf = wv + 8*qf
  const short* bp0 = dmFn + ((size_t)((wv)      * 16) * 512) + lane * 8;
  const short* bp1 = dmFn + ((size_t)((wv + 8)  * 16) * 512) + lane * 8;
  const short* bp2 = dmFn + ((size_t)((wv + 16) * 16) * 512) + lane * 8;
  const short* bp3 = dmFn + ((size_t)((wv + 24) * 16) * 512) + lane * 8;
  const int kq0 = wv >> 1, kq1 = (wv + 8) >> 1, kq2 = (wv + 16) >> 1;
  const int kmaxw = (wv + 24) >> 1;   // in [12,15]

  for (int kblk = 0; kblk <= kmaxw; ++kblk) {
    GEMM_TRIP(kblk);
  }

  // fused dot: part[m] = sum_q Y[m,q] * basis[m,q]; one b64 per (rf,qf)
  float part[16];
#pragma unroll
  for (int x = 0; x < 16; ++x) part[x] = 0.0f;
  uint qp[4];
#pragma unroll
  for (int qf = 0; qf < 4; ++qf) {
    int q = (wv + 8 * qf) * 16 + li;
    qp[qf] = ((uint)(q >> 5) << 10) + (((uint)(q >> 2) & 1u) << 9)
           + (((uint)(q & 31) >> 3) << 7) + ((uint)(q & 3) << 5) + ((uint)kg << 3);
  }
#pragma unroll
  for (int rf = 0; rf < 4; ++rf) {
#pragma unroll
    for (int qf = 0; qf < 4; ++qf) {
      union { u32x2 u; _Float16 h[4]; } dd;
      dd.u = *(const u32x2*)(smem + ((uint)rf << 14) + qp[qf]);
      part[rf * 4 + 0] = fmaf(acc[rf][qf][0], (float)dd.h[0], part[rf * 4 + 0]);
      part[rf * 4 + 1] = fmaf(acc[rf][qf][1], (float)dd.h[1], part[rf * 4 + 1]);
      part[rf * 4 + 2] = fmaf(acc[rf][qf][2], (float)dd.h[2], part[rf * 4 + 2]);
      part[rf * 4 + 3] = fmaf(acc[rf][qf][3], (float)dd.h[3], part[rf * 4 + 3]);
    }
  }

  // ---------------- reduce + store (atomic-free, deterministic) ----------------
  __syncthreads();   // all basis reads done before rbuf overwrites tiles
#pragma unroll
  for (int x = 0; x < 16; ++x) {
    float v = part[x];
    v += __shfl_xor(v, 1);
    v += __shfl_xor(v, 2);
    v += __shfl_xor(v, 4);
    v += __shfl_xor(v, 8);
    part[x] = v;
  }
  float* rbuf = (float*)smem;
  if (li == 0) {
#pragma unroll
    for (int rf = 0; rf < 4; ++rf)
#pragma unroll
      for (int jj = 0; jj < 4; ++jj)
        rbuf[wv * 64 + rf * 16 + kg * 4 + jj] = part[rf * 4 + jj];
  }
  __syncthreads();
  if (t < BM) {
    float s = 0.0f;
#pragma unroll
    for (int w = 0; w < 8; ++w) s += rbuf[w * 64 + t];
    out[(size_t)n * MS + m0 + t] = s;
  }
}

extern "C" void kernel_launch(void* const* d_in, const int* in_sizes, int n_in,
                              void* d_out, int out_size, void* d_ws, size_t ws_size,
                              hipStream_t stream) {
  const float* dv      = (const float*)d_in[0];
  const int*   centers = (const int*)d_in[1];
  const float* expg    = (const float*)d_in[2];
  const int*   sym     = (const int*)d_in[3];
  const float* dm      = (const float*)d_in[4];
  float* out = (float*)d_out;

  char* ws = (char*)d_ws;
  short* dmF    = (short*)(ws + WS_DMF_OFF);
  uint*  m2a    = (uint*)(ws + WS_M2A_OFF);
  uint*  m2b    = (uint*)(ws + WS_M2B_OFF);
  float* alphaS = (float*)(ws + WS_ALPH_OFF);

  dm_pack<<<dim3(16, NMOL), 256, 0, stream>>>(dm, dmF, centers, sym, expg,
                                              m2a, m2b, alphaS);
  wfn_fused8<<<dim3(NMOL * (MS / BM)), 512, 0, stream>>>(dv, m2a, m2b, alphaS, dmF, out);
}